// Round 9
// baseline (427.614 us; speedup 1.0000x reference)
//
#include <hip/hip_runtime.h>
#include <stdint.h>

#define B_   512
#define D_   1024
#define N_   8192
#define M_   2048
#define K_   4
#define WSP  320
#define KACT 40
#define NW   128   // N_/64 bit-words per row

typedef _Float16 f16;
typedef _Float16 f16x4 __attribute__((ext_vector_type(4)));
typedef _Float16 f16x8 __attribute__((ext_vector_type(8)));
typedef float f32x4 __attribute__((ext_vector_type(4)));

#define BM 128
#define BN 128
#define SPLIT_SCALE 2048.0f
#define SPLIT_INV (1.0f / 2048.0f)

#define GLD16(g, l) __builtin_amdgcn_global_load_lds( \
    (const __attribute__((address_space(1))) uint32_t*)(g), \
    (__attribute__((address_space(3))) uint32_t*)(l), 16, 0, 0)

// ---------------------------------------------------------------------------
// Stage 0: splitS (unchanged)
__global__ __launch_bounds__(256) void splitS_kernel(const float* __restrict__ S,
                                                     uint8_t* __restrict__ imgA) {
    int blk = blockIdx.x;            // mt*32 + dstep
    int mt = blk >> 5, dstep = blk & 31;
    int tid = threadIdx.x;
    uint8_t* outb = imgA + (size_t)blk * 16384;
#pragma unroll
    for (int q = 0; q < 4; q++) {
        int o = tid * 16 + q * 4096;
        int r = o >> 7, inner = o & 127;
        int sw = (r & 7) << 4;
        int raw = inner ^ sw;
        int plane = raw >> 6;
        int k0 = (raw & 63) >> 1;
        const float* sp = &S[(size_t)(mt * 128 + r) * D_ + dstep * 32 + k0];
        float4 v0 = *(const float4*)sp;
        float4 v1 = *(const float4*)(sp + 4);
        f16x8 out;
        if (plane == 0) {
            out[0] = (f16)v0.x; out[1] = (f16)v0.y; out[2] = (f16)v0.z; out[3] = (f16)v0.w;
            out[4] = (f16)v1.x; out[5] = (f16)v1.y; out[6] = (f16)v1.z; out[7] = (f16)v1.w;
        } else {
            f16 h0 = (f16)v0.x, h1 = (f16)v0.y, h2 = (f16)v0.z, h3 = (f16)v0.w;
            f16 h4 = (f16)v1.x, h5 = (f16)v1.y, h6 = (f16)v1.z, h7 = (f16)v1.w;
            out[0] = (f16)((v0.x - (float)h0) * SPLIT_SCALE);
            out[1] = (f16)((v0.y - (float)h1) * SPLIT_SCALE);
            out[2] = (f16)((v0.z - (float)h2) * SPLIT_SCALE);
            out[3] = (f16)((v0.w - (float)h3) * SPLIT_SCALE);
            out[4] = (f16)((v1.x - (float)h4) * SPLIT_SCALE);
            out[5] = (f16)((v1.y - (float)h5) * SPLIT_SCALE);
            out[6] = (f16)((v1.z - (float)h6) * SPLIT_SCALE);
            out[7] = (f16)((v1.w - (float)h7) * SPLIT_SCALE);
        }
        *(f16x8*)&outb[o] = out;
    }
}

// ---------------------------------------------------------------------------
// Stage 1: gemm 128x128, 4 waves, 64 KB dbuf, 2 blocks/CU, counted vmcnt (R8)
// + 4-PHASE SPLIT (m201 pattern): per dstep, 4 x {B-frag reads -> s_barrier ->
// setprio + 12 MFMA} with staging distributed (W-issue + A-reads ph0, GLD16
// ph1, pack_write after ph3), one lgkm-drained end barrier. Short barrier-
// aligned MFMA clusters let waves leapfrog: reads/stage of phase p+1 issue
// under other waves' phase-p MFMAs (R7 probe: monolithic phases = convoy).
__device__ __forceinline__ void pack_write_B(uint8_t* Bn, const float* w,
                                             int kc0, int bn, int bsw) {
#pragma unroll
    for (int kci = 0; kci < 2; kci++) {
        int kc = kc0 * 2 + kci;
        f16x8 hv, lv;
#pragma unroll
        for (int j = 0; j < 8; j++) {
            float x = w[kci * 8 + j];
            f16 h = (f16)x;
            hv[j] = h;
            lv[j] = (f16)((x - (float)h) * SPLIT_SCALE);
        }
        *(f16x8*)&Bn[bn * 128 + ((kc * 16) ^ bsw)] = hv;
        *(f16x8*)&Bn[bn * 128 + ((64 + kc * 16) ^ bsw)] = lv;
    }
}

__global__ __launch_bounds__(256, 2) void gemm_kernel(const uint8_t* __restrict__ imgA,
                                                      const float* __restrict__ W,
                                                      float* __restrict__ C) {
    // [0,32K): A dbuf (2 x 16 KB). [32K,64K): B dbuf (2 x 16 KB).
    __shared__ __align__(16) uint8_t lds[65536];

    int bid = blockIdx.x;
    int l = (bid & 7) * 128 + (bid >> 3);  // XCD-contiguous remap (1024 % 8 == 0)
    int mt = l & 3, nt = (l >> 2) & 63, kt = l >> 8;

    int tid = threadIdx.x;
    int wave = tid >> 6, lane = tid & 63;
    int wm = wave >> 1, wn = wave & 1;     // 2 m-waves x 2 n-waves
    int lr = lane & 15, lg = lane >> 4;

    const uint8_t* srcA0 = imgA + (size_t)(mt * 32) * 16384 + wave * 1024 + lane * 16;
    const float* Wp = W + (size_t)kt * D_ * N_ + nt * BN;
    float* Cp = C + (size_t)kt * B_ * N_ + (size_t)(mt * BM) * N_ + nt * BN;

    int bn = tid & 127;
    int kc0 = tid >> 7;                    // 0..1
    int bsw = (bn & 7) << 4;

    f32x4 acc0[4][4], acc1[4][4];
#pragma unroll
    for (int i = 0; i < 4; i++)
#pragma unroll
        for (int j = 0; j < 4; j++) {
            acc0[i][j] = (f32x4){0.f, 0.f, 0.f, 0.f};
            acc1[i][j] = (f32x4){0.f, 0.f, 0.f, 0.f};
        }

    // ---- prologue: stage dstep 0 into buffer 0; GLD16(0) stays outstanding
    {
        float w[16];
        const float* wp0 = Wp + (size_t)(kc0 * 16) * N_ + bn;
#pragma unroll
        for (int j = 0; j < 16; j++) w[j] = wp0[(size_t)j * N_];
        uint8_t* dA = lds + wave * 1024;
#pragma unroll
        for (int q = 0; q < 4; q++)
            GLD16(srcA0 + q * 4096, dA + q * 4096);
        pack_write_B(lds + 32768, w, kc0, bn, bsw);   // compiler waits W(0) via w[]
        asm volatile("s_waitcnt lgkmcnt(0)" ::: "memory");
        __builtin_amdgcn_s_barrier();
    }

    for (int dstep = 0; dstep < 32; dstep++) {
        int cur = dstep & 1;
        uint8_t* Ac = lds + cur * 16384;
        uint8_t* Bc = lds + 32768 + cur * 16384;
        bool pf = (dstep < 31);

        // ---- phase 0 front: issue 16 W(t+1) loads; counted wait for GLD16(t)
        float wreg[16];
        if (pf) {
            const float* wp0 = Wp + (size_t)((dstep + 1) * 32 + kc0 * 16) * N_ + bn;
#pragma unroll
            for (int j = 0; j < 16; j++) wreg[j] = wp0[(size_t)j * N_];
            // outstanding: 4 GLD16(t) [oldest] + 16 W(t+1); wait only the GLD16s
            asm volatile("s_waitcnt vmcnt(16)" ::: "memory");
        } else {
            asm volatile("s_waitcnt vmcnt(0)" ::: "memory");
        }

        // A-frag reads (used by every phase's MFMAs)
        f16x8 ah[4], al[4];
#pragma unroll
        for (int i = 0; i < 4; i++) {
            int r = wm * 64 + i * 16 + lr;
            int sw = (r & 7) << 4;
            ah[i] = *(const f16x8*)&Ac[r * 128 + ((lg * 16) ^ sw)];
            al[i] = *(const f16x8*)&Ac[r * 128 + ((64 + lg * 16) ^ sw)];
        }

        // ---- 4 phases: {B-frag reads; [ph1: GLD16 A(t+1)]; barrier; 12 MFMA}
#pragma unroll
        for (int jj = 0; jj < 4; jj++) {
            int n = wn * 64 + jj * 16 + lr;
            int sw = (n & 7) << 4;
            f16x8 bh = *(const f16x8*)&Bc[n * 128 + ((lg * 16) ^ sw)];
            f16x8 bl = *(const f16x8*)&Bc[n * 128 + ((64 + lg * 16) ^ sw)];
            if (jj == 1 && pf) {
                const uint8_t* sA = srcA0 + (size_t)(dstep + 1) * 16384;
                uint8_t* dA = lds + (cur ^ 1) * 16384 + wave * 1024;
#pragma unroll
                for (int q = 0; q < 4; q++)
                    GLD16(sA + q * 4096, dA + q * 4096);
            }
            __builtin_amdgcn_s_barrier();          // phase alignment (no drain)
            __builtin_amdgcn_s_setprio(1);
#pragma unroll
            for (int i = 0; i < 4; i++) {
                acc0[i][jj] = __builtin_amdgcn_mfma_f32_16x16x32_f16(ah[i], bh, acc0[i][jj], 0, 0, 0);
                acc1[i][jj] = __builtin_amdgcn_mfma_f32_16x16x32_f16(ah[i], bl, acc1[i][jj], 0, 0, 0);
                acc1[i][jj] = __builtin_amdgcn_mfma_f32_16x16x32_f16(al[i], bh, acc1[i][jj], 0, 0, 0);
            }
            __builtin_amdgcn_s_setprio(0);
        }

        // ---- write-late: split W(t+1) into other B buffer (vmcnt(4) implicit)
        if (pf)
            pack_write_B(lds + 32768 + (cur ^ 1) * 16384, wreg, kc0, bn, bsw);

        // ---- end-of-dstep: drain LDS writes only; GLD16/W stay in flight
        asm volatile("s_waitcnt lgkmcnt(0)" ::: "memory");
        __builtin_amdgcn_s_barrier();
    }

    // ---- epilogue: C = acc0 + acc1/2048. C frag: col=lane&15, row=(lane>>4)*4+reg
#pragma unroll
    for (int i = 0; i < 4; i++)
#pragma unroll
        for (int jj = 0; jj < 4; jj++) {
            int r0 = wm * 64 + i * 16 + lg * 4;
            int c0 = wn * 64 + jj * 16 + lr;
#pragma unroll
            for (int r = 0; r < 4; r++)
                Cp[(size_t)(r0 + r) * N_ + c0] = acc0[i][jj][r] + acc1[i][jj][r] * SPLIT_INV;
        }
}

// ---------------------------------------------------------------------------
// Stage 2 (fused, interleaved; R4-validated, unchanged)
__global__ __launch_bounds__(256) void select_conn_kernel(const float* __restrict__ scores,
                                                          uint32_t* __restrict__ sdr_bits32,
                                                          const float* __restrict__ perm,
                                                          uint32_t* __restrict__ conn32,
                                                          int* __restrict__ mcount) {
    int bid = blockIdx.x;
    int tid = threadIdx.x;
    if (bid % 5 != 0) {
        int km = bid - (bid / 5) - 1;     // 0..8191
        if (tid == 0) mcount[km] = 0;
        const float* p = perm + (size_t)km * N_ + tid * 32;
        uint32_t bits = 0;
#pragma unroll
        for (int q = 0; q < 8; q++) {
            float4 v = *(const float4*)&p[q * 4];
            bits |= (v.x >= 0.5f ? 1u : 0u) << (q * 4 + 0);
            bits |= (v.y >= 0.5f ? 1u : 0u) << (q * 4 + 1);
            bits |= (v.z >= 0.5f ? 1u : 0u) << (q * 4 + 2);
            bits |= (v.w >= 0.5f ? 1u : 0u) << (q * 4 + 3);
        }
        conn32[(size_t)km * 256 + tid] = bits;
        return;
    }

    __shared__ int hist[256];
    __shared__ int wsum[4];
    __shared__ int wgt[4];
    __shared__ uint32_t sh_prefix;
    __shared__ int sh_r;

    int kb = bid / 5;                 // k*B_ + b
    int lane = tid & 63, w = tid >> 6;
    const float* row = scores + (size_t)kb * N_ + tid * 32;

    uint32_t key[32];
#pragma unroll
    for (int q = 0; q < 8; q++) {
        float4 v = *(const float4*)&row[q * 4];
        uint32_t u0 = __float_as_uint(v.x), u1 = __float_as_uint(v.y);
        uint32_t u2 = __float_as_uint(v.z), u3 = __float_as_uint(v.w);
        key[q * 4 + 0] = (u0 & 0x80000000u) ? ~u0 : (u0 | 0x80000000u);
        key[q * 4 + 1] = (u1 & 0x80000000u) ? ~u1 : (u1 | 0x80000000u);
        key[q * 4 + 2] = (u2 & 0x80000000u) ? ~u2 : (u2 | 0x80000000u);
        key[q * 4 + 3] = (u3 & 0x80000000u) ? ~u3 : (u3 | 0x80000000u);
    }
    if (tid == 0) { sh_prefix = 0u; sh_r = WSP; }
    hist[tid] = 0;
    __syncthreads();

    for (int p = 3; p >= 0; p--) {
        uint32_t prefix = sh_prefix;
        int r = sh_r;
        uint32_t maskHi = (p == 3) ? 0u : (0xFFFFFFFFu << ((p + 1) * 8));
        int shift = p * 8;
#pragma unroll
        for (int j = 0; j < 32; j++) {
            uint32_t u = key[j];
            if ((u & maskHi) == prefix) atomicAdd(&hist[(u >> shift) & 255], 1);
        }
        __syncthreads();
        int h = hist[tid];
        int S = h;
#pragma unroll
        for (int off = 1; off < 64; off <<= 1) {
            int t2 = __shfl_down(S, off);
            if (lane + off < 64) S += t2;
        }
        if (lane == 0) wsum[w] = S;
        __syncthreads();
        int above = 0;
#pragma unroll
        for (int ww = 0; ww < 4; ww++) above += (ww > w) ? wsum[ww] : 0;
        int G = S + above;
        int Gn = G - h;
        if (G >= r && Gn < r) { sh_prefix = prefix | ((uint32_t)tid << shift); sh_r = r - Gn; }
        hist[tid] = 0;
        __syncthreads();
    }
    uint32_t t = sh_prefix;

    int gt = 0, eq = 0;
#pragma unroll
    for (int j = 0; j < 32; j++) {
        gt += (key[j] > t); eq += (key[j] == t);
    }
    int eI = eq;
#pragma unroll
    for (int off = 1; off < 64; off <<= 1) {
        int t3 = __shfl_up(eI, off);
        if (lane >= off) eI += t3;
    }
    int gT = gt;
#pragma unroll
    for (int off = 1; off < 64; off <<= 1) gT += __shfl_xor(gT, off);
    if (lane == 63) wsum[w] = eI;
    if (lane == 0) wgt[w] = gT;
    __syncthreads();
    int eqoff = 0;
#pragma unroll
    for (int ww = 0; ww < 4; ww++) eqoff += (ww < w) ? wsum[ww] : 0;
    int totalGt = wgt[0] + wgt[1] + wgt[2] + wgt[3];
    int eb = eqoff + eI - eq;
    int r_eq = WSP - totalGt;

    uint32_t bits = 0;
#pragma unroll
    for (int j = 0; j < 32; j++) {
        uint32_t u = key[j];
        bool f = (u > t) || ((u == t) && (eb < r_eq));
        if (u == t) eb++;
        if (f) bits |= (1u << j);
    }
    sdr_bits32[(size_t)kb * 256 + tid] = bits;
}

// ---------------------------------------------------------------------------
// Stage 3a: overlap matrix (unchanged)
#define OV_BBLK 16
#define OV_MTILE 512
__global__ __launch_bounds__(256) void overlap_mat_kernel(const uint64_t* __restrict__ sdr_bits,
                                                          const uint64_t* __restrict__ conn,
                                                          uint16_t* __restrict__ ovmat) {
    __shared__ uint64_t sw[OV_BBLK][NW];   // 16 KB

    int bid = blockIdx.x;                  // 0..511
    int nb = (bid & 7) * 64 + (bid >> 3);  // XCD chunk
    int k = nb >> 7;
    int rem = nb & 127;
    int b0 = (rem >> 2) * OV_BBLK;
    int m0 = (rem & 3) * OV_MTILE;
    int tid = threadIdx.x;

    for (int i = tid; i < OV_BBLK * NW; i += 256) {
        int bb = i >> 7, w = i & 127;
        sw[bb][w] = sdr_bits[((size_t)k * B_ + b0 + bb) * NW + w];
    }
    __syncthreads();

    int m_a = m0 + tid;
    int m_b = m0 + tid + 256;
    const ulonglong2* cra = (const ulonglong2*)(conn + ((size_t)k * M_ + m_a) * NW);
    const ulonglong2* crb = (const ulonglong2*)(conn + ((size_t)k * M_ + m_b) * NW);

    int acca[OV_BBLK], accb[OV_BBLK];
#pragma unroll
    for (int i = 0; i < OV_BBLK; i++) { acca[i] = 0; accb[i] = 0; }

#pragma unroll 2
    for (int wp = 0; wp < NW / 2; wp++) {
        ulonglong2 ca = cra[wp];
        ulonglong2 cb = crb[wp];
#pragma unroll
        for (int bb = 0; bb < OV_BBLK; bb++) {
            ulonglong2 s = *(const ulonglong2*)&sw[bb][wp * 2];
            acca[bb] += __popcll(ca.x & s.x) + __popcll(ca.y & s.y);
            accb[bb] += __popcll(cb.x & s.x) + __popcll(cb.y & s.y);
        }
    }
#pragma unroll
    for (int bb = 0; bb < OV_BBLK; bb++) {
        ovmat[((size_t)k * B_ + b0 + bb) * M_ + m_a] = (uint16_t)acca[bb];
        ovmat[((size_t)k * B_ + b0 + bb) * M_ + m_b] = (uint16_t)accb[bb];
    }
}

// ---------------------------------------------------------------------------
// Stage 3b (fused, interleaved; unchanged)
__global__ __launch_bounds__(256) void top40_cons_kernel(const uint16_t* __restrict__ ovmat,
                                                         int* __restrict__ mcount,
                                                         int* __restrict__ mlist,
                                                         const uint64_t* __restrict__ sdr_bits,
                                                         float* __restrict__ cons,
                                                         float* __restrict__ sdr0) {
    int bid = blockIdx.x;
    int tid = threadIdx.x;
    if (bid % 9 != 0) {
        int gid = (bid - (bid / 9) - 1) * 256 + tid;
        int b = gid >> 13;
        int n = gid & (N_ - 1);
        int wi = n >> 6, bit = n & 63;
        size_t base = (size_t)b * NW + wi;
        uint64_t w0 = sdr_bits[base];
        uint64_t w1 = sdr_bits[(size_t)1 * B_ * NW + base];
        uint64_t w2 = sdr_bits[(size_t)2 * B_ * NW + base];
        uint64_t w3 = sdr_bits[(size_t)3 * B_ * NW + base];
        uint64_t a = w0 & w1 & w2 & w3;
        cons[gid] = (float)((a >> bit) & 1);
        sdr0[gid] = (float)((w0 >> bit) & 1);
        return;
    }

    __shared__ int hist[512];
    __shared__ int wsA[4], wsB[4];
    __shared__ int sh_t, sh_req;

    int kb = bid / 9;                 // k*B_ + b
    int k = kb >> 9;
    int b = kb & 511;
    int lane = tid & 63, w = tid >> 6;

    union { uint4 raw; uint16_t v[8]; } ov;
    ov.raw = *(const uint4*)&ovmat[(size_t)kb * M_ + tid * 8];

    hist[tid] = 0; hist[tid + 256] = 0;
    __syncthreads();
#pragma unroll
    for (int j = 0; j < 8; j++) atomicAdd(&hist[ov.v[j]], 1);
    __syncthreads();

    int hL = hist[tid], hH = hist[tid + 256];
    int SL = hL, SH = hH;
#pragma unroll
    for (int off = 1; off < 64; off <<= 1) {
        int a0 = __shfl_down(SL, off);
        int a1 = __shfl_down(SH, off);
        if (lane + off < 64) { SL += a0; SH += a1; }
    }
    if (lane == 0) { wsA[w] = SL; wsB[w] = SH; }
    __syncthreads();
    int aboveA = 0, aboveB = 0, totH = 0;
#pragma unroll
    for (int ww = 0; ww < 4; ww++) {
        aboveA += (ww > w) ? wsA[ww] : 0;
        aboveB += (ww > w) ? wsB[ww] : 0;
        totH += wsB[ww];
    }
    int GL = SL + aboveA + totH;
    int GH = SH + aboveB;
    int GnL = GL - hL, GnH = GH - hH;
    if (GL >= KACT && GnL < KACT) { sh_t = tid; sh_req = KACT - GnL; }
    if (GH >= KACT && GnH < KACT) { sh_t = tid + 256; sh_req = KACT - GnH; }
    __syncthreads();
    int t = sh_t, req = sh_req;

    int eq = 0;
#pragma unroll
    for (int j = 0; j < 8; j++) eq += (ov.v[j] == t);
    int eI = eq;
#pragma unroll
    for (int off = 1; off < 64; off <<= 1) {
        int t3 = __shfl_up(eI, off);
        if (lane >= off) eI += t3;
    }
    if (lane == 63) wsA[w] = eI;
    __syncthreads();
    int eqoff = 0;
#pragma unroll
    for (int ww = 0; ww < 4; ww++) eqoff += (ww < w) ? wsA[ww] : 0;
    int eb = eqoff + eI - eq;

#pragma unroll
    for (int j = 0; j < 8; j++) {
        int m = tid * 8 + j;
        int v2 = ov.v[j];
        bool act = (v2 > t) || (v2 == t && eb < req);
        if (v2 == t) eb++;
        if (act) {
            int pos = atomicAdd(&mcount[k * M_ + m], 1);
            mlist[(((size_t)k * M_ + m) << 9) + pos] = b;
        }
    }
}

// ---------------------------------------------------------------------------
// Stage 5: update (unchanged)
__global__ __launch_bounds__(512) void update_kernel(const float* __restrict__ perm,
                                                     const uint64_t* __restrict__ sdr_bits,
                                                     const int* __restrict__ mcount,
                                                     const int* __restrict__ mlist,
                                                     float* __restrict__ pout) {
    __shared__ int blist[512];
    int km = blockIdx.x;
    int k = km / M_;
    int tid = threadIdx.x;
    int cnt = mcount[km];
    for (int i = tid; i < cnt; i += 512) blist[i] = mlist[((size_t)km << 9) + i];
    __syncthreads();

    int n0 = tid * 16;
    int c[16];
#pragma unroll
    for (int j = 0; j < 16; j++) c[j] = 0;
    int wi = n0 >> 6;
    int sh = n0 & 63;
    const uint64_t* sb = sdr_bits + (size_t)k * B_ * NW;

#define LDROW(idx) sb[(size_t)blist[idx] * NW + wi]
#define ACC(x) { unsigned bb_ = (unsigned)(((x) >> sh) & 0xFFFFu); \
                 _Pragma("unroll") for (int j = 0; j < 16; j++) c[j] += (bb_ >> j) & 1; }

    uint64_t p0 = 0, p1 = 0, p2 = 0, p3 = 0, p4 = 0, p5 = 0, p6 = 0, p7 = 0;
    if (cnt > 0) p0 = LDROW(0);
    if (cnt > 1) p1 = LDROW(1);
    if (cnt > 2) p2 = LDROW(2);
    if (cnt > 3) p3 = LDROW(3);
    if (cnt > 4) p4 = LDROW(4);
    if (cnt > 5) p5 = LDROW(5);
    if (cnt > 6) p6 = LDROW(6);
    if (cnt > 7) p7 = LDROW(7);

    for (int base = 0; base < cnt; base += 8) {
        uint64_t c0 = p0, c1 = p1, c2 = p2, c3 = p3, c4 = p4, c5 = p5, c6 = p6, c7 = p7;
        int nx = base + 8;
        if (nx + 0 < cnt) p0 = LDROW(nx + 0);
        if (nx + 1 < cnt) p1 = LDROW(nx + 1);
        if (nx + 2 < cnt) p2 = LDROW(nx + 2);
        if (nx + 3 < cnt) p3 = LDROW(nx + 3);
        if (nx + 4 < cnt) p4 = LDROW(nx + 4);
        if (nx + 5 < cnt) p5 = LDROW(nx + 5);
        if (nx + 6 < cnt) p6 = LDROW(nx + 6);
        if (nx + 7 < cnt) p7 = LDROW(nx + 7);
        int nv = cnt - base;
        ACC(c0);
        if (nv > 1) ACC(c1);
        if (nv > 2) ACC(c2);
        if (nv > 3) ACC(c3);
        if (nv > 4) ACC(c4);
        if (nv > 5) ACC(c5);
        if (nv > 6) ACC(c6);
        if (nv > 7) ACC(c7);
    }
#undef LDROW
#undef ACC

    const float scale = (float)(0.01 / 512.0);
    const float* pr = perm + (size_t)km * N_ + n0;
    float* po = pout + (size_t)km * N_ + n0;
#pragma unroll
    for (int q = 0; q < 4; q++) {
        float4 pv = *(const float4*)&pr[q * 4];
        float4 o;
        o.x = fminf(fmaxf(pv.x + scale * (float)(2 * c[q * 4 + 0] - cnt), 0.f), 1.f);
        o.y = fminf(fmaxf(pv.y + scale * (float)(2 * c[q * 4 + 1] - cnt), 0.f), 1.f);
        o.z = fminf(fmaxf(pv.z + scale * (float)(2 * c[q * 4 + 2] - cnt), 0.f), 1.f);
        o.w = fminf(fmaxf(pv.w + scale * (float)(2 * c[q * 4 + 3] - cnt), 0.f), 1.f);
        *(float4*)&po[q * 4] = o;
    }
}

// ---------------------------------------------------------------------------
extern "C" void kernel_launch(void* const* d_in, const int* in_sizes, int n_in,
                              void* d_out, int out_size, void* d_ws, size_t ws_size,
                              hipStream_t stream) {
    const float* s_batch = (const float*)d_in[0];
    const float* W_enc   = (const float*)d_in[1];
    const float* perm    = (const float*)d_in[2];

    float* out  = (float*)d_out;
    float* cons = out;
    float* sdr0 = out + (size_t)B_ * N_;
    float* pout = out + (size_t)2 * B_ * N_;

    char* ws = (char*)d_ws;
    float*    scores   = (float*)ws;                                  // 64 MB
    uint16_t* ovmat    = (uint16_t*)ws;                               // 8 MB, overlays dead scores
    uint64_t* sdr_bits = (uint64_t*)(ws + ((size_t)64 << 20));        // 2 MB
    uint64_t* conn     = (uint64_t*)(ws + ((size_t)66 << 20));        // 8 MB
    int*      mcount   = (int*)(ws + ((size_t)74 << 20));             // 32 KB
    int*      mlist    = (int*)(ws + ((size_t)75 << 20));             // 16 MB
    uint8_t*  imgA     = (uint8_t*)(ws + ((size_t)92 << 20));         // 2 MB

    splitS_kernel<<<4 * 32, 256, 0, stream>>>(s_batch, imgA);

    gemm_kernel<<<K_ * (B_ / BM) * (N_ / BN), 256, 0, stream>>>(imgA, W_enc, scores);

    select_conn_kernel<<<2048 * 5, 256, 0, stream>>>(
        scores, (uint32_t*)sdr_bits, perm, (uint32_t*)conn, mcount);

    overlap_mat_kernel<<<K_ * (B_ / OV_BBLK) * (M_ / OV_MTILE), 256, 0, stream>>>(
        sdr_bits, conn, ovmat);

    top40_cons_kernel<<<2048 * 9, 256, 0, stream>>>(
        ovmat, mcount, mlist, sdr_bits, cons, sdr0);

    update_kernel<<<K_ * M_, 512, 0, stream>>>(perm, sdr_bits, mcount, mlist, pout);
}

// Round 10
// 416.628 us; speedup vs baseline: 1.0264x; 1.0264x over previous
//
#include <hip/hip_runtime.h>
#include <stdint.h>

#define B_   512
#define D_   1024
#define N_   8192
#define M_   2048
#define K_   4
#define WSP  320
#define KACT 40
#define NW   128   // N_/64 bit-words per row

typedef _Float16 f16;
typedef _Float16 f16x4 __attribute__((ext_vector_type(4)));
typedef _Float16 f16x8 __attribute__((ext_vector_type(8)));
typedef float f32x4 __attribute__((ext_vector_type(4)));

#define BM 128
#define BN 128
#define SPLIT_SCALE 2048.0f
#define SPLIT_INV (1.0f / 2048.0f)

#define GLD16(g, l) __builtin_amdgcn_global_load_lds( \
    (const __attribute__((address_space(1))) uint32_t*)(g), \
    (__attribute__((address_space(3))) uint32_t*)(l), 16, 0, 0)

// ---------------------------------------------------------------------------
// Stage 0: splitS (unchanged)
__global__ __launch_bounds__(256) void splitS_kernel(const float* __restrict__ S,
                                                     uint8_t* __restrict__ imgA) {
    int blk = blockIdx.x;            // mt*32 + dstep
    int mt = blk >> 5, dstep = blk & 31;
    int tid = threadIdx.x;
    uint8_t* outb = imgA + (size_t)blk * 16384;
#pragma unroll
    for (int q = 0; q < 4; q++) {
        int o = tid * 16 + q * 4096;
        int r = o >> 7, inner = o & 127;
        int sw = (r & 7) << 4;
        int raw = inner ^ sw;
        int plane = raw >> 6;
        int k0 = (raw & 63) >> 1;
        const float* sp = &S[(size_t)(mt * 128 + r) * D_ + dstep * 32 + k0];
        float4 v0 = *(const float4*)sp;
        float4 v1 = *(const float4*)(sp + 4);
        f16x8 out;
        if (plane == 0) {
            out[0] = (f16)v0.x; out[1] = (f16)v0.y; out[2] = (f16)v0.z; out[3] = (f16)v0.w;
            out[4] = (f16)v1.x; out[5] = (f16)v1.y; out[6] = (f16)v1.z; out[7] = (f16)v1.w;
        } else {
            f16 h0 = (f16)v0.x, h1 = (f16)v0.y, h2 = (f16)v0.z, h3 = (f16)v0.w;
            f16 h4 = (f16)v1.x, h5 = (f16)v1.y, h6 = (f16)v1.z, h7 = (f16)v1.w;
            out[0] = (f16)((v0.x - (float)h0) * SPLIT_SCALE);
            out[1] = (f16)((v0.y - (float)h1) * SPLIT_SCALE);
            out[2] = (f16)((v0.z - (float)h2) * SPLIT_SCALE);
            out[3] = (f16)((v0.w - (float)h3) * SPLIT_SCALE);
            out[4] = (f16)((v1.x - (float)h4) * SPLIT_SCALE);
            out[5] = (f16)((v1.y - (float)h5) * SPLIT_SCALE);
            out[6] = (f16)((v1.z - (float)h6) * SPLIT_SCALE);
            out[7] = (f16)((v1.w - (float)h7) * SPLIT_SCALE);
        }
        *(f16x8*)&outb[o] = out;
    }
}

// ---------------------------------------------------------------------------
// Stage 1: gemm — EXACT R6 version (best validated: 419.7 us total).
// 128x128 tile, 4 waves, 64 KB LDS dbuf, 2 blocks/CU, single __syncthreads
// per K-step. R8 (counted vmcnt) and R9 (phase split) were null/regressive:
// this quadrant doesn't respond to T3/T4 — structure frozen.
__device__ __forceinline__ void pack_write_B(uint8_t* Bn, const float* w,
                                             int kc0, int bn, int bsw) {
#pragma unroll
    for (int kci = 0; kci < 2; kci++) {
        int kc = kc0 * 2 + kci;
        f16x8 hv, lv;
#pragma unroll
        for (int j = 0; j < 8; j++) {
            float x = w[kci * 8 + j];
            f16 h = (f16)x;
            hv[j] = h;
            lv[j] = (f16)((x - (float)h) * SPLIT_SCALE);
        }
        *(f16x8*)&Bn[bn * 128 + ((kc * 16) ^ bsw)] = hv;
        *(f16x8*)&Bn[bn * 128 + ((64 + kc * 16) ^ bsw)] = lv;
    }
}

__global__ __launch_bounds__(256, 2) void gemm_kernel(const uint8_t* __restrict__ imgA,
                                                      const float* __restrict__ W,
                                                      float* __restrict__ C) {
    // [0,32K): A dbuf (2 x 16 KB). [32K,64K): B dbuf (2 x 16 KB).
    __shared__ __align__(16) uint8_t lds[65536];

    int bid = blockIdx.x;
    int l = (bid & 7) * 128 + (bid >> 3);  // XCD-contiguous remap (1024 % 8 == 0)
    int mt = l & 3, nt = (l >> 2) & 63, kt = l >> 8;

    int tid = threadIdx.x;
    int wave = tid >> 6, lane = tid & 63;
    int wm = wave >> 1, wn = wave & 1;     // 2 m-waves x 2 n-waves
    int lr = lane & 15, lg = lane >> 4;

    const uint8_t* srcA0 = imgA + (size_t)(mt * 32) * 16384 + wave * 1024 + lane * 16;
    const float* Wp = W + (size_t)kt * D_ * N_ + nt * BN;
    float* Cp = C + (size_t)kt * B_ * N_ + (size_t)(mt * BM) * N_ + nt * BN;

    int bn = tid & 127;
    int kc0 = tid >> 7;                    // 0..1
    int bsw = (bn & 7) << 4;

    f32x4 acc0[4][4], acc1[4][4];
#pragma unroll
    for (int i = 0; i < 4; i++)
#pragma unroll
        for (int j = 0; j < 4; j++) {
            acc0[i][j] = (f32x4){0.f, 0.f, 0.f, 0.f};
            acc1[i][j] = (f32x4){0.f, 0.f, 0.f, 0.f};
        }

    // ---- prologue: stage dstep 0 into buffer 0
    {
        uint8_t* dA = lds + wave * 1024;
#pragma unroll
        for (int q = 0; q < 4; q++)
            GLD16(srcA0 + q * 4096, dA + q * 4096);
        float w[16];
        const float* wp0 = Wp + (size_t)(kc0 * 16) * N_ + bn;
#pragma unroll
        for (int j = 0; j < 16; j++) w[j] = wp0[(size_t)j * N_];
        pack_write_B(lds + 32768, w, kc0, bn, bsw);
    }
    __syncthreads();

    for (int dstep = 0; dstep < 32; dstep++) {
        int cur = dstep & 1;
        uint8_t* Ac = lds + cur * 16384;
        uint8_t* Bc = lds + 32768 + cur * 16384;
        bool pf = (dstep < 31);

        // ---- early issue: next A tile (async to LDS), next W rows (to regs)
        float wreg[16];
        if (pf) {
            const uint8_t* sA = srcA0 + (size_t)(dstep + 1) * 16384;
            uint8_t* dA = lds + (cur ^ 1) * 16384 + wave * 1024;
#pragma unroll
            for (int q = 0; q < 4; q++)
                GLD16(sA + q * 4096, dA + q * 4096);
            const float* wp0 = Wp + (size_t)((dstep + 1) * 32 + kc0 * 16) * N_ + bn;
#pragma unroll
            for (int j = 0; j < 16; j++) wreg[j] = wp0[(size_t)j * N_];
        }

        // ---- compute current buffer
        f16x8 ah[4], al[4];
#pragma unroll
        for (int i = 0; i < 4; i++) {
            int r = wm * 64 + i * 16 + lr;
            int sw = (r & 7) << 4;
            ah[i] = *(const f16x8*)&Ac[r * 128 + ((lg * 16) ^ sw)];
            al[i] = *(const f16x8*)&Ac[r * 128 + ((64 + lg * 16) ^ sw)];
        }
#pragma unroll
        for (int jj = 0; jj < 4; jj++) {
            int n = wn * 64 + jj * 16 + lr;
            int sw = (n & 7) << 4;
            f16x8 bh = *(const f16x8*)&Bc[n * 128 + ((lg * 16) ^ sw)];
            f16x8 bl = *(const f16x8*)&Bc[n * 128 + ((64 + lg * 16) ^ sw)];
            __builtin_amdgcn_s_setprio(1);
#pragma unroll
            for (int i = 0; i < 4; i++) {
                acc0[i][jj] = __builtin_amdgcn_mfma_f32_16x16x32_f16(ah[i], bh, acc0[i][jj], 0, 0, 0);
                acc1[i][jj] = __builtin_amdgcn_mfma_f32_16x16x32_f16(ah[i], bl, acc1[i][jj], 0, 0, 0);
                acc1[i][jj] = __builtin_amdgcn_mfma_f32_16x16x32_f16(al[i], bh, acc1[i][jj], 0, 0, 0);
            }
            __builtin_amdgcn_s_setprio(0);
        }

        // ---- write-late: split next W regs into the other B buffer
        if (pf)
            pack_write_B(lds + 32768 + (cur ^ 1) * 16384, wreg, kc0, bn, bsw);

        __syncthreads();   // single barrier/K-step
    }

    // ---- epilogue: C = acc0 + acc1/2048. C frag: col=lane&15, row=(lane>>4)*4+reg
#pragma unroll
    for (int i = 0; i < 4; i++)
#pragma unroll
        for (int jj = 0; jj < 4; jj++) {
            int r0 = wm * 64 + i * 16 + lg * 4;
            int c0 = wn * 64 + jj * 16 + lr;
#pragma unroll
            for (int r = 0; r < 4; r++)
                Cp[(size_t)(r0 + r) * N_ + c0] = acc0[i][jj][r] + acc1[i][jj][r] * SPLIT_INV;
        }
}

// ---------------------------------------------------------------------------
// Stage 2 (fused, interleaved): bid%5==0 -> select (2048), else conn (8192).
// SELECT REWORK: 3 passes of 11/11/10 bits over a 2048-bin LDS hist
// (8 bins/thread, int4 zero/read). Scores' top byte concentrates in ~5 of
// 256 bins (N(0,32) exponent clustering) -> the old 8-bit pass-3 serialized
// ~1400 same-address LDS atomics; 11-bit digits fold 3 mantissa bits into
// the first pass (~70 active bins), and passes 2-3 see only the surviving
// prefix's keys. Keys stay in registers (R1/R6 structure); wave-level scan
// (R4); digit decomposition validated end-to-end in R2.
__global__ __launch_bounds__(256) void select_conn_kernel(const float* __restrict__ scores,
                                                          uint32_t* __restrict__ sdr_bits32,
                                                          const float* __restrict__ perm,
                                                          uint32_t* __restrict__ conn32,
                                                          int* __restrict__ mcount) {
    int bid = blockIdx.x;
    int tid = threadIdx.x;
    if (bid % 5 != 0) {
        int km = bid - (bid / 5) - 1;     // 0..8191
        if (tid == 0) mcount[km] = 0;
        const float* p = perm + (size_t)km * N_ + tid * 32;
        uint32_t bits = 0;
#pragma unroll
        for (int q = 0; q < 8; q++) {
            float4 v = *(const float4*)&p[q * 4];
            bits |= (v.x >= 0.5f ? 1u : 0u) << (q * 4 + 0);
            bits |= (v.y >= 0.5f ? 1u : 0u) << (q * 4 + 1);
            bits |= (v.z >= 0.5f ? 1u : 0u) << (q * 4 + 2);
            bits |= (v.w >= 0.5f ? 1u : 0u) << (q * 4 + 3);
        }
        conn32[(size_t)km * 256 + tid] = bits;
        return;
    }

    __shared__ int hist[2048];        // 8 KB
    __shared__ int wsum[4];
    __shared__ int wgt[4];
    __shared__ uint32_t sh_prefix;
    __shared__ int sh_r;

    int kb = bid / 5;                 // k*B_ + b
    int lane = tid & 63, w = tid >> 6;
    const float* row = scores + (size_t)kb * N_ + tid * 32;

    uint32_t key[32];
#pragma unroll
    for (int q = 0; q < 8; q++) {
        float4 v = *(const float4*)&row[q * 4];
        uint32_t u0 = __float_as_uint(v.x), u1 = __float_as_uint(v.y);
        uint32_t u2 = __float_as_uint(v.z), u3 = __float_as_uint(v.w);
        key[q * 4 + 0] = (u0 & 0x80000000u) ? ~u0 : (u0 | 0x80000000u);
        key[q * 4 + 1] = (u1 & 0x80000000u) ? ~u1 : (u1 | 0x80000000u);
        key[q * 4 + 2] = (u2 & 0x80000000u) ? ~u2 : (u2 | 0x80000000u);
        key[q * 4 + 3] = (u3 & 0x80000000u) ? ~u3 : (u3 | 0x80000000u);
    }
    if (tid == 0) { sh_prefix = 0u; sh_r = WSP; }
    {
        int4 z4 = {0, 0, 0, 0};
        *(int4*)&hist[tid * 8] = z4;
        *(int4*)&hist[tid * 8 + 4] = z4;
    }
    __syncthreads();

    for (int p = 0; p < 3; p++) {
        const int shift = (p == 0) ? 21 : (p == 1) ? 10 : 0;
        const uint32_t hm = (p == 0) ? 0u : (p == 1) ? 0xFFE00000u : 0xFFFFFC00u;
        const uint32_t dm = (p == 2) ? 1023u : 2047u;
        uint32_t prefix = sh_prefix;
        int r = sh_r;
#pragma unroll
        for (int j = 0; j < 32; j++) {
            uint32_t u = key[j];
            if ((u & hm) == prefix) atomicAdd(&hist[(u >> shift) & dm], 1);
        }
        __syncthreads();
        int h[8];
        *(int4*)&h[0] = *(const int4*)&hist[tid * 8];
        *(int4*)&h[4] = *(const int4*)&hist[tid * 8 + 4];
        int own = 0;
#pragma unroll
        for (int i = 0; i < 8; i++) own += h[i];
        // wave suffix-inclusive scan over per-thread totals (ascending bins)
        int S = own;
#pragma unroll
        for (int off = 1; off < 64; off <<= 1) {
            int t2 = __shfl_down(S, off);
            if (lane + off < 64) S += t2;
        }
        if (lane == 0) wsum[w] = S;
        __syncthreads();
        int above = 0;
#pragma unroll
        for (int ww = 0; ww < 4; ww++) above += (ww > w) ? wsum[ww] : 0;
        int G = S + above;       // suffix over bins >= tid*8
        int Gn = G - own;        // suffix over bins >= (tid+1)*8
        if (G >= r && Gn < r) {
            // crossing is inside this thread's 8 bins
            int acc = Gn, dig = 0, newr = 0;
#pragma unroll
            for (int i = 7; i >= 0; i--) {
                int prev = acc;
                acc += h[i];
                if (acc >= r && prev < r) { dig = tid * 8 + i; newr = r - prev; }
            }
            sh_prefix = prefix | ((uint32_t)dig << shift);
            sh_r = newr;
        }
        // re-zero own bins for next pass
        {
            int4 z4 = {0, 0, 0, 0};
            *(int4*)&hist[tid * 8] = z4;
            *(int4*)&hist[tid * 8 + 4] = z4;
        }
        __syncthreads();
    }
    uint32_t t = sh_prefix;

    int gt = 0, eq = 0;
#pragma unroll
    for (int j = 0; j < 32; j++) {
        gt += (key[j] > t); eq += (key[j] == t);
    }
    int eI = eq;
#pragma unroll
    for (int off = 1; off < 64; off <<= 1) {
        int t3 = __shfl_up(eI, off);
        if (lane >= off) eI += t3;
    }
    int gT = gt;
#pragma unroll
    for (int off = 1; off < 64; off <<= 1) gT += __shfl_xor(gT, off);
    if (lane == 63) wsum[w] = eI;         // wave eq total
    if (lane == 0) wgt[w] = gT;           // wave gt total
    __syncthreads();
    int eqoff = 0;
#pragma unroll
    for (int ww = 0; ww < 4; ww++) eqoff += (ww < w) ? wsum[ww] : 0;
    int totalGt = wgt[0] + wgt[1] + wgt[2] + wgt[3];
    int eb = eqoff + eI - eq;             // exclusive prefix of eq
    int r_eq = WSP - totalGt;

    uint32_t bits = 0;
#pragma unroll
    for (int j = 0; j < 32; j++) {
        uint32_t u = key[j];
        bool f = (u > t) || ((u == t) && (eb < r_eq));
        if (u == t) eb++;
        if (f) bits |= (1u << j);
    }
    sdr_bits32[(size_t)kb * 256 + tid] = bits;
}

// ---------------------------------------------------------------------------
// Stage 3a: overlap matrix (unchanged)
#define OV_BBLK 16
#define OV_MTILE 512
__global__ __launch_bounds__(256) void overlap_mat_kernel(const uint64_t* __restrict__ sdr_bits,
                                                          const uint64_t* __restrict__ conn,
                                                          uint16_t* __restrict__ ovmat) {
    __shared__ uint64_t sw[OV_BBLK][NW];   // 16 KB

    int bid = blockIdx.x;                  // 0..511
    int nb = (bid & 7) * 64 + (bid >> 3);  // XCD chunk
    int k = nb >> 7;
    int rem = nb & 127;
    int b0 = (rem >> 2) * OV_BBLK;
    int m0 = (rem & 3) * OV_MTILE;
    int tid = threadIdx.x;

    for (int i = tid; i < OV_BBLK * NW; i += 256) {
        int bb = i >> 7, w = i & 127;
        sw[bb][w] = sdr_bits[((size_t)k * B_ + b0 + bb) * NW + w];
    }
    __syncthreads();

    int m_a = m0 + tid;
    int m_b = m0 + tid + 256;
    const ulonglong2* cra = (const ulonglong2*)(conn + ((size_t)k * M_ + m_a) * NW);
    const ulonglong2* crb = (const ulonglong2*)(conn + ((size_t)k * M_ + m_b) * NW);

    int acca[OV_BBLK], accb[OV_BBLK];
#pragma unroll
    for (int i = 0; i < OV_BBLK; i++) { acca[i] = 0; accb[i] = 0; }

#pragma unroll 2
    for (int wp = 0; wp < NW / 2; wp++) {
        ulonglong2 ca = cra[wp];
        ulonglong2 cb = crb[wp];
#pragma unroll
        for (int bb = 0; bb < OV_BBLK; bb++) {
            ulonglong2 s = *(const ulonglong2*)&sw[bb][wp * 2];
            acca[bb] += __popcll(ca.x & s.x) + __popcll(ca.y & s.y);
            accb[bb] += __popcll(cb.x & s.x) + __popcll(cb.y & s.y);
        }
    }
#pragma unroll
    for (int bb = 0; bb < OV_BBLK; bb++) {
        ovmat[((size_t)k * B_ + b0 + bb) * M_ + m_a] = (uint16_t)acca[bb];
        ovmat[((size_t)k * B_ + b0 + bb) * M_ + m_b] = (uint16_t)accb[bb];
    }
}

// ---------------------------------------------------------------------------
// Stage 3b (fused, interleaved; unchanged)
__global__ __launch_bounds__(256) void top40_cons_kernel(const uint16_t* __restrict__ ovmat,
                                                         int* __restrict__ mcount,
                                                         int* __restrict__ mlist,
                                                         const uint64_t* __restrict__ sdr_bits,
                                                         float* __restrict__ cons,
                                                         float* __restrict__ sdr0) {
    int bid = blockIdx.x;
    int tid = threadIdx.x;
    if (bid % 9 != 0) {
        int gid = (bid - (bid / 9) - 1) * 256 + tid;
        int b = gid >> 13;
        int n = gid & (N_ - 1);
        int wi = n >> 6, bit = n & 63;
        size_t base = (size_t)b * NW + wi;
        uint64_t w0 = sdr_bits[base];
        uint64_t w1 = sdr_bits[(size_t)1 * B_ * NW + base];
        uint64_t w2 = sdr_bits[(size_t)2 * B_ * NW + base];
        uint64_t w3 = sdr_bits[(size_t)3 * B_ * NW + base];
        uint64_t a = w0 & w1 & w2 & w3;
        cons[gid] = (float)((a >> bit) & 1);
        sdr0[gid] = (float)((w0 >> bit) & 1);
        return;
    }

    __shared__ int hist[512];
    __shared__ int wsA[4], wsB[4];
    __shared__ int sh_t, sh_req;

    int kb = bid / 9;                 // k*B_ + b
    int k = kb >> 9;
    int b = kb & 511;
    int lane = tid & 63, w = tid >> 6;

    union { uint4 raw; uint16_t v[8]; } ov;
    ov.raw = *(const uint4*)&ovmat[(size_t)kb * M_ + tid * 8];

    hist[tid] = 0; hist[tid + 256] = 0;
    __syncthreads();
#pragma unroll
    for (int j = 0; j < 8; j++) atomicAdd(&hist[ov.v[j]], 1);
    __syncthreads();

    int hL = hist[tid], hH = hist[tid + 256];
    int SL = hL, SH = hH;
#pragma unroll
    for (int off = 1; off < 64; off <<= 1) {
        int a0 = __shfl_down(SL, off);
        int a1 = __shfl_down(SH, off);
        if (lane + off < 64) { SL += a0; SH += a1; }
    }
    if (lane == 0) { wsA[w] = SL; wsB[w] = SH; }
    __syncthreads();
    int aboveA = 0, aboveB = 0, totH = 0;
#pragma unroll
    for (int ww = 0; ww < 4; ww++) {
        aboveA += (ww > w) ? wsA[ww] : 0;
        aboveB += (ww > w) ? wsB[ww] : 0;
        totH += wsB[ww];
    }
    int GL = SL + aboveA + totH;
    int GH = SH + aboveB;
    int GnL = GL - hL, GnH = GH - hH;
    if (GL >= KACT && GnL < KACT) { sh_t = tid; sh_req = KACT - GnL; }
    if (GH >= KACT && GnH < KACT) { sh_t = tid + 256; sh_req = KACT - GnH; }
    __syncthreads();
    int t = sh_t, req = sh_req;

    int eq = 0;
#pragma unroll
    for (int j = 0; j < 8; j++) eq += (ov.v[j] == t);
    int eI = eq;
#pragma unroll
    for (int off = 1; off < 64; off <<= 1) {
        int t3 = __shfl_up(eI, off);
        if (lane >= off) eI += t3;
    }
    if (lane == 63) wsA[w] = eI;
    __syncthreads();
    int eqoff = 0;
#pragma unroll
    for (int ww = 0; ww < 4; ww++) eqoff += (ww < w) ? wsA[ww] : 0;
    int eb = eqoff + eI - eq;

#pragma unroll
    for (int j = 0; j < 8; j++) {
        int m = tid * 8 + j;
        int v2 = ov.v[j];
        bool act = (v2 > t) || (v2 == t && eb < req);
        if (v2 == t) eb++;
        if (act) {
            int pos = atomicAdd(&mcount[k * M_ + m], 1);
            mlist[(((size_t)k * M_ + m) << 9) + pos] = b;
        }
    }
}

// ---------------------------------------------------------------------------
// Stage 5: update (unchanged — at its 512 MB HBM floor)
__global__ __launch_bounds__(512) void update_kernel(const float* __restrict__ perm,
                                                     const uint64_t* __restrict__ sdr_bits,
                                                     const int* __restrict__ mcount,
                                                     const int* __restrict__ mlist,
                                                     float* __restrict__ pout) {
    __shared__ int blist[512];
    int km = blockIdx.x;
    int k = km / M_;
    int tid = threadIdx.x;
    int cnt = mcount[km];
    for (int i = tid; i < cnt; i += 512) blist[i] = mlist[((size_t)km << 9) + i];
    __syncthreads();

    int n0 = tid * 16;
    int c[16];
#pragma unroll
    for (int j = 0; j < 16; j++) c[j] = 0;
    int wi = n0 >> 6;
    int sh = n0 & 63;
    const uint64_t* sb = sdr_bits + (size_t)k * B_ * NW;

#define LDROW(idx) sb[(size_t)blist[idx] * NW + wi]
#define ACC(x) { unsigned bb_ = (unsigned)(((x) >> sh) & 0xFFFFu); \
                 _Pragma("unroll") for (int j = 0; j < 16; j++) c[j] += (bb_ >> j) & 1; }

    uint64_t p0 = 0, p1 = 0, p2 = 0, p3 = 0, p4 = 0, p5 = 0, p6 = 0, p7 = 0;
    if (cnt > 0) p0 = LDROW(0);
    if (cnt > 1) p1 = LDROW(1);
    if (cnt > 2) p2 = LDROW(2);
    if (cnt > 3) p3 = LDROW(3);
    if (cnt > 4) p4 = LDROW(4);
    if (cnt > 5) p5 = LDROW(5);
    if (cnt > 6) p6 = LDROW(6);
    if (cnt > 7) p7 = LDROW(7);

    for (int base = 0; base < cnt; base += 8) {
        uint64_t c0 = p0, c1 = p1, c2 = p2, c3 = p3, c4 = p4, c5 = p5, c6 = p6, c7 = p7;
        int nx = base + 8;
        if (nx + 0 < cnt) p0 = LDROW(nx + 0);
        if (nx + 1 < cnt) p1 = LDROW(nx + 1);
        if (nx + 2 < cnt) p2 = LDROW(nx + 2);
        if (nx + 3 < cnt) p3 = LDROW(nx + 3);
        if (nx + 4 < cnt) p4 = LDROW(nx + 4);
        if (nx + 5 < cnt) p5 = LDROW(nx + 5);
        if (nx + 6 < cnt) p6 = LDROW(nx + 6);
        if (nx + 7 < cnt) p7 = LDROW(nx + 7);
        int nv = cnt - base;
        ACC(c0);
        if (nv > 1) ACC(c1);
        if (nv > 2) ACC(c2);
        if (nv > 3) ACC(c3);
        if (nv > 4) ACC(c4);
        if (nv > 5) ACC(c5);
        if (nv > 6) ACC(c6);
        if (nv > 7) ACC(c7);
    }
#undef LDROW
#undef ACC

    const float scale = (float)(0.01 / 512.0);
    const float* pr = perm + (size_t)km * N_ + n0;
    float* po = pout + (size_t)km * N_ + n0;
#pragma unroll
    for (int q = 0; q < 4; q++) {
        float4 pv = *(const float4*)&pr[q * 4];
        float4 o;
        o.x = fminf(fmaxf(pv.x + scale * (float)(2 * c[q * 4 + 0] - cnt), 0.f), 1.f);
        o.y = fminf(fmaxf(pv.y + scale * (float)(2 * c[q * 4 + 1] - cnt), 0.f), 1.f);
        o.z = fminf(fmaxf(pv.z + scale * (float)(2 * c[q * 4 + 2] - cnt), 0.f), 1.f);
        o.w = fminf(fmaxf(pv.w + scale * (float)(2 * c[q * 4 + 3] - cnt), 0.f), 1.f);
        *(float4*)&po[q * 4] = o;
    }
}

// ---------------------------------------------------------------------------
extern "C" void kernel_launch(void* const* d_in, const int* in_sizes, int n_in,
                              void* d_out, int out_size, void* d_ws, size_t ws_size,
                              hipStream_t stream) {
    const float* s_batch = (const float*)d_in[0];
    const float* W_enc   = (const float*)d_in[1];
    const float* perm    = (const float*)d_in[2];

    float* out  = (float*)d_out;
    float* cons = out;
    float* sdr0 = out + (size_t)B_ * N_;
    float* pout = out + (size_t)2 * B_ * N_;

    char* ws = (char*)d_ws;
    float*    scores   = (float*)ws;                                  // 64 MB
    uint16_t* ovmat    = (uint16_t*)ws;                               // 8 MB, overlays dead scores
    uint64_t* sdr_bits = (uint64_t*)(ws + ((size_t)64 << 20));        // 2 MB
    uint64_t* conn     = (uint64_t*)(ws + ((size_t)66 << 20));        // 8 MB
    int*      mcount   = (int*)(ws + ((size_t)74 << 20));             // 32 KB
    int*      mlist    = (int*)(ws + ((size_t)75 << 20));             // 16 MB
    uint8_t*  imgA     = (uint8_t*)(ws + ((size_t)92 << 20));         // 2 MB

    splitS_kernel<<<4 * 32, 256, 0, stream>>>(s_batch, imgA);

    gemm_kernel<<<K_ * (B_ / BM) * (N_ / BN), 256, 0, stream>>>(imgA, W_enc, scores);

    select_conn_kernel<<<2048 * 5, 256, 0, stream>>>(
        scores, (uint32_t*)sdr_bits, perm, (uint32_t*)conn, mcount);

    overlap_mat_kernel<<<K_ * (B_ / OV_BBLK) * (M_ / OV_MTILE), 256, 0, stream>>>(
        sdr_bits, conn, ovmat);

    top40_cons_kernel<<<2048 * 9, 256, 0, stream>>>(
        ovmat, mcount, mlist, sdr_bits, cons, sdr0);

    update_kernel<<<K_ * M_, 512, 0, stream>>>(perm, sdr_bits, mcount, mlist, pout);
}